// Round 1
// baseline (419.555 us; speedup 1.0000x reference)
//
#include <hip/hip_runtime.h>
#include <hip/hip_bf16.h>
#include <math.h>

#define BB 8
#define MM 8192
#define DD 512
#define RR 64
#define HH 128

__device__ __forceinline__ float gelu_tanh(float x) {
    // jax.nn.gelu approximate=True: 0.5x(1+tanh(sqrt(2/pi)(x+0.044715x^3)))
    float u = 0.7978845608028654f * (x + 0.044715f * x * x * x);
    float e = __expf(2.0f * u);
    float t = 1.0f - 2.0f / (e + 1.0f);   // tanh(u), safe for |u| large
    return 0.5f * x * (1.0f + t);
}

// ---------------- Kernel A: add path (512 rows, tiny) ----------------
__global__ __launch_bounds__(256) void add_path_kernel(
    const float* __restrict__ ot, const float* __restrict__ scale,
    const float* __restrict__ bias, const float* __restrict__ Wa1,
    const float* __restrict__ ba1, const float* __restrict__ Wa2,
    const float* __restrict__ ba2, float* __restrict__ add_out)
{
    int tid = threadIdx.x;
    int b = blockIdx.x >> 6, r = blockIdx.x & 63;
    const float* x = ot + (size_t)(b * RR + r) * DD;
    __shared__ float xs[DD];
    __shared__ float hsm[HH];
    __shared__ float rs[4], rq[4];
    float v0 = x[tid], v1 = x[tid + 256];
    float s = v0 + v1, q = v0 * v0 + v1 * v1;
    #pragma unroll
    for (int off = 32; off > 0; off >>= 1) { s += __shfl_xor(s, off); q += __shfl_xor(q, off); }
    if ((tid & 63) == 0) { rs[tid >> 6] = s; rq[tid >> 6] = q; }
    __syncthreads();
    s = rs[0] + rs[1] + rs[2] + rs[3];
    q = rq[0] + rq[1] + rq[2] + rq[3];
    float mean = s * (1.0f / DD);
    float var = q * (1.0f / DD) - mean * mean;
    float inv = rsqrtf(var + 1e-6f);
    xs[tid]       = (v0 - mean) * inv * scale[tid]       + bias[tid];
    xs[tid + 256] = (v1 - mean) * inv * scale[tid + 256] + bias[tid + 256];
    __syncthreads();
    if (tid < HH) {
        float acc = ba1[tid];
        for (int k = 0; k < DD; k++) acc = fmaf(xs[k], Wa1[k * HH + tid], acc);
        hsm[tid] = gelu_tanh(acc);
    }
    __syncthreads();
    int d0 = tid, d1 = tid + 256;
    float a0 = ba2[d0], a1 = ba2[d1];
    #pragma unroll 4
    for (int k = 0; k < HH; k++) {
        float hk = hsm[k];
        a0 = fmaf(hk, Wa2[k * DD + d0], a0);
        a1 = fmaf(hk, Wa2[k * DD + d1], a1);
    }
    add_out[(size_t)(b * RR + r) * DD + d0] = a0;
    add_out[(size_t)(b * RR + r) * DD + d1] = a1;
}

// ---------------- Kernel B: erase logits (LN + 512x128 GEMM + gelu + 128x64 GEMM) ----
// One block = 32 memory rows. LDS: xn[32][512] f32 (64KB), reused as hs[32][132].
__global__ __launch_bounds__(256) void erase_logits_kernel(
    const float* __restrict__ mem, const float* __restrict__ scale,
    const float* __restrict__ bias, const float* __restrict__ We1,
    const float* __restrict__ be1, const float* __restrict__ We2,
    const float* __restrict__ be2, float* __restrict__ logits)
{
    __shared__ float xn[32 * 512];
    int tid = threadIdx.x;
    int b = blockIdx.x >> 8;
    int m0 = (blockIdx.x & 255) * 32;
    const float* src = mem + (size_t)(b * MM + m0) * DD;
    for (int idx = tid; idx < 32 * DD; idx += 256) xn[idx] = src[idx];
    __syncthreads();
    // per-wave LN over 8 rows each
    int wave = tid >> 6, lane = tid & 63;
    float sc[8], bi[8];
    #pragma unroll
    for (int j = 0; j < 8; j++) { sc[j] = scale[j * 64 + lane]; bi[j] = bias[j * 64 + lane]; }
    for (int row = wave; row < 32; row += 4) {
        float vv[8], s = 0.0f, q = 0.0f;
        #pragma unroll
        for (int j = 0; j < 8; j++) { float v = xn[row * 512 + j * 64 + lane]; vv[j] = v; s += v; q += v * v; }
        #pragma unroll
        for (int off = 32; off > 0; off >>= 1) { s += __shfl_xor(s, off); q += __shfl_xor(q, off); }
        float mean = s * (1.0f / 512.0f);
        float var = q * (1.0f / 512.0f) - mean * mean;
        float inv = rsqrtf(var + 1e-6f);
        #pragma unroll
        for (int j = 0; j < 8; j++)
            xn[row * 512 + j * 64 + lane] = (vv[j] - mean) * inv * sc[j] + bi[j];
    }
    __syncthreads();
    // GEMM1: thread (tr,tc) computes rows tr*4..+3, cols tc*4..+3
    int tr = tid >> 5, tc = tid & 31;
    const float4* We1v = (const float4*)We1;
    float4 b1 = ((const float4*)be1)[tc];
    float4 acc0 = b1, acc1 = b1, acc2 = b1, acc3 = b1;
    #pragma unroll 4
    for (int k = 0; k < 512; k++) {
        float4 w = We1v[k * 32 + tc];
        float x0 = xn[(tr * 4 + 0) * 512 + k];
        float x1 = xn[(tr * 4 + 1) * 512 + k];
        float x2 = xn[(tr * 4 + 2) * 512 + k];
        float x3 = xn[(tr * 4 + 3) * 512 + k];
        acc0.x = fmaf(x0, w.x, acc0.x); acc0.y = fmaf(x0, w.y, acc0.y);
        acc0.z = fmaf(x0, w.z, acc0.z); acc0.w = fmaf(x0, w.w, acc0.w);
        acc1.x = fmaf(x1, w.x, acc1.x); acc1.y = fmaf(x1, w.y, acc1.y);
        acc1.z = fmaf(x1, w.z, acc1.z); acc1.w = fmaf(x1, w.w, acc1.w);
        acc2.x = fmaf(x2, w.x, acc2.x); acc2.y = fmaf(x2, w.y, acc2.y);
        acc2.z = fmaf(x2, w.z, acc2.z); acc2.w = fmaf(x2, w.w, acc2.w);
        acc3.x = fmaf(x3, w.x, acc3.x); acc3.y = fmaf(x3, w.y, acc3.y);
        acc3.z = fmaf(x3, w.z, acc3.z); acc3.w = fmaf(x3, w.w, acc3.w);
    }
    __syncthreads();   // everyone done reading xn
    float* hs = xn;    // overlay: hs[32][132]
    {
        float4 a[4] = {acc0, acc1, acc2, acc3};
        #pragma unroll
        for (int i = 0; i < 4; i++) {
            int base = (tr * 4 + i) * 132 + tc * 4;
            hs[base + 0] = gelu_tanh(a[i].x);
            hs[base + 1] = gelu_tanh(a[i].y);
            hs[base + 2] = gelu_tanh(a[i].z);
            hs[base + 3] = gelu_tanh(a[i].w);
        }
    }
    __syncthreads();
    // GEMM2: thread (rr,cg): row rr, cols cg*8..+7
    int rr = tid >> 3, cg = tid & 7;
    const float4* We2v = (const float4*)We2;
    float4 alo = ((const float4*)be2)[cg * 2 + 0];
    float4 ahi = ((const float4*)be2)[cg * 2 + 1];
    #pragma unroll 4
    for (int k = 0; k < 128; k++) {
        float hk = hs[rr * 132 + k];
        float4 wl = We2v[k * 16 + cg * 2 + 0];
        float4 wh = We2v[k * 16 + cg * 2 + 1];
        alo.x = fmaf(hk, wl.x, alo.x); alo.y = fmaf(hk, wl.y, alo.y);
        alo.z = fmaf(hk, wl.z, alo.z); alo.w = fmaf(hk, wl.w, alo.w);
        ahi.x = fmaf(hk, wh.x, ahi.x); ahi.y = fmaf(hk, wh.y, ahi.y);
        ahi.z = fmaf(hk, wh.z, ahi.z); ahi.w = fmaf(hk, wh.w, ahi.w);
    }
    float* dst = logits + ((size_t)(b * MM + m0 + rr)) * 64 + cg * 8;
    ((float4*)dst)[0] = alo;
    ((float4*)dst)[1] = ahi;
}

// ---------------- Kernel 3a: per-(b,r) online max/sumexp over 512-row chunks ----------
__global__ __launch_bounds__(256) void softmax_partial_kernel(
    const float* __restrict__ logits, float* __restrict__ pmax, float* __restrict__ psum)
{
    int tid = threadIdx.x;
    int b = blockIdx.x >> 4, ch = blockIdx.x & 15;
    int g = tid >> 6, r = tid & 63;
    int m0 = ch * 512;
    float mx = -1e30f, sm = 0.0f;
    for (int i = 0; i < 128; i++) {
        int m = m0 + g + i * 4;
        float v = logits[((size_t)(b * MM + m)) * 64 + r];
        float nm = fmaxf(mx, v);
        sm = sm * __expf(mx - nm) + __expf(v - nm);
        mx = nm;
    }
    __shared__ float smax[4][64], ssum[4][64];
    smax[g][r] = mx; ssum[g][r] = sm;
    __syncthreads();
    if (tid < 64) {
        float M_ = smax[0][tid], S_ = ssum[0][tid];
        #pragma unroll
        for (int gg = 1; gg < 4; gg++) {
            float m2 = smax[gg][tid], s2 = ssum[gg][tid];
            float nm = fmaxf(M_, m2);
            S_ = S_ * __expf(M_ - nm) + s2 * __expf(m2 - nm);
            M_ = nm;
        }
        pmax[(size_t)(b * 16 + ch) * 64 + tid] = M_;
        psum[(size_t)(b * 16 + ch) * 64 + tid] = S_;
    }
}

// ---------------- Kernel 3b: combine 16 chunk partials -> rmax, rinv ------------------
__global__ void softmax_finalize_kernel(const float* __restrict__ pmax,
                                        const float* __restrict__ psum,
                                        float* __restrict__ rmax, float* __restrict__ rinv)
{
    int b = blockIdx.x;
    int r = threadIdx.x; // 64 threads
    float mx = -1e30f, sm = 0.0f;
    for (int ch = 0; ch < 16; ch++) {
        float m2 = pmax[(size_t)(b * 16 + ch) * 64 + r];
        float s2 = psum[(size_t)(b * 16 + ch) * 64 + r];
        float nm = fmaxf(mx, m2);
        sm = sm * __expf(mx - nm) + s2 * __expf(m2 - nm);
        mx = nm;
    }
    rmax[b * 64 + r] = mx;
    rinv[b * 64 + r] = 1.0f / sm;
}

// ---------------- Kernel 4: ea = softmax_weights @ add; out = mem + ea*(1-mem) --------
// One block: one batch b, 128 memory rows. Dynamic LDS: add[64][512] f32 + w[16][64] + stats.
__global__ __launch_bounds__(256) void apply_kernel(
    const float* __restrict__ mem, const float* __restrict__ logits,
    const float* __restrict__ add, const float* __restrict__ rmax,
    const float* __restrict__ rinv, float* __restrict__ out)
{
    extern __shared__ float lds[];
    float* addl  = lds;                 // 64*512
    float* wlds  = lds + 64 * 512;      // 16*64
    float* rmaxl = wlds + 16 * 64;      // 64
    float* rinvl = rmaxl + 64;          // 64
    int tid = threadIdx.x;
    int b = blockIdx.x >> 6, mt = blockIdx.x & 63;
    int m0 = mt * 128;
    const float* asrc = add + (size_t)b * RR * DD;
    for (int idx = tid; idx < RR * DD; idx += 256) addl[idx] = asrc[idx];
    if (tid < 64) { rmaxl[tid] = rmax[b * 64 + tid]; rinvl[tid] = rinv[b * 64 + tid]; }
    __syncthreads();
    int rg = tid >> 7, c = tid & 127;
    for (int p = 0; p < 8; p++) {
        int mp = m0 + p * 16;
        #pragma unroll
        for (int i = 0; i < 4; i++) {
            int fl = tid + 256 * i;
            int row = fl >> 6, r = fl & 63;
            float w = __expf(logits[((size_t)(b * MM + mp + row)) * 64 + r] - rmaxl[r]) * rinvl[r];
            wlds[row * 64 + r] = w;
        }
        __syncthreads();
        float4 acc[8];
        #pragma unroll
        for (int i = 0; i < 8; i++) acc[i] = make_float4(0.f, 0.f, 0.f, 0.f);
        for (int r = 0; r < 64; r++) {
            float4 a4 = *(const float4*)&addl[r * 512 + c * 4];
            #pragma unroll
            for (int i = 0; i < 8; i++) {
                float w = wlds[(rg * 8 + i) * 64 + r];
                acc[i].x = fmaf(w, a4.x, acc[i].x);
                acc[i].y = fmaf(w, a4.y, acc[i].y);
                acc[i].z = fmaf(w, a4.z, acc[i].z);
                acc[i].w = fmaf(w, a4.w, acc[i].w);
            }
        }
        #pragma unroll
        for (int i = 0; i < 8; i++) {
            int m = mp + rg * 8 + i;
            float4 mv = *(const float4*)&mem[((size_t)(b * MM + m)) * DD + c * 4];
            float4 o;
            o.x = fmaf(acc[i].x, 1.0f - mv.x, mv.x);
            o.y = fmaf(acc[i].y, 1.0f - mv.y, mv.y);
            o.z = fmaf(acc[i].z, 1.0f - mv.z, mv.z);
            o.w = fmaf(acc[i].w, 1.0f - mv.w, mv.w);
            *(float4*)&out[((size_t)(b * MM + m)) * DD + c * 4] = o;
        }
        __syncthreads();
    }
}

extern "C" void kernel_launch(void* const* d_in, const int* in_sizes, int n_in,
                              void* d_out, int out_size, void* d_ws, size_t ws_size,
                              hipStream_t stream) {
    const float* memory = (const float*)d_in[0];
    const float* ot     = (const float*)d_in[1];
    const float* ln_e_s = (const float*)d_in[2];
    const float* ln_e_b = (const float*)d_in[3];
    const float* We1    = (const float*)d_in[4];
    const float* be1    = (const float*)d_in[5];
    const float* We2    = (const float*)d_in[6];
    const float* be2    = (const float*)d_in[7];
    const float* ln_a_s = (const float*)d_in[8];
    const float* ln_a_b = (const float*)d_in[9];
    const float* Wa1    = (const float*)d_in[10];
    const float* ba1    = (const float*)d_in[11];
    const float* Wa2    = (const float*)d_in[12];
    const float* ba2    = (const float*)d_in[13];
    float* out = (float*)d_out;

    float* ws      = (float*)d_ws;
    float* add_ws  = ws;                        // 262144 floats (1 MB)
    float* logits  = ws + 262144;               // 4194304 floats (16 MB)
    float* pmaxw   = ws + 262144 + 4194304;     // 8192
    float* psumw   = pmaxw + 8192;              // 8192
    float* rmaxw   = psumw + 8192;              // 512
    float* rinvw   = rmaxw + 512;               // 512

    hipLaunchKernelGGL(add_path_kernel, dim3(BB * RR), dim3(256), 0, stream,
                       ot, ln_a_s, ln_a_b, Wa1, ba1, Wa2, ba2, add_ws);
    hipLaunchKernelGGL(erase_logits_kernel, dim3(BB * (MM / 32)), dim3(256), 0, stream,
                       memory, ln_e_s, ln_e_b, We1, be1, We2, be2, logits);
    hipLaunchKernelGGL(softmax_partial_kernel, dim3(BB * 16), dim3(256), 0, stream,
                       logits, pmaxw, psumw);
    hipLaunchKernelGGL(softmax_finalize_kernel, dim3(BB), dim3(64), 0, stream,
                       pmaxw, psumw, rmaxw, rinvw);

    size_t k4_lds = (size_t)(64 * 512 + 16 * 64 + 128) * sizeof(float); // 135,680 B
    hipFuncSetAttribute((const void*)apply_kernel,
                        hipFuncAttributeMaxDynamicSharedMemorySize, (int)k4_lds);
    hipLaunchKernelGGL(apply_kernel, dim3(BB * 64), dim3(256), k4_lds, stream,
                       memory, logits, add_ws, rmaxw, rinvw, out);
}

// Round 2
// 272.065 us; speedup vs baseline: 1.5421x; 1.5421x over previous
//
#include <hip/hip_runtime.h>
#include <hip/hip_bf16.h>
#include <math.h>

#define BB 8
#define MM 8192
#define DD 512
#define RR 64
#define HH 128

typedef __attribute__((ext_vector_type(8))) short bf16x8;
typedef __attribute__((ext_vector_type(4))) float f32x4;

#define XN_LD 520   // bf16 elems per xn row (512 + 8 pad -> 1040B stride, 16B aligned)
#define H_LD  136   // bf16 elems per h row  (128 + 8 pad -> 272B stride, 16B aligned)

__device__ __forceinline__ float gelu_tanh(float x) {
    float u = 0.7978845608028654f * (x + 0.044715f * x * x * x);
    float e = __expf(2.0f * u);
    float t = 1.0f - 2.0f / (e + 1.0f);   // tanh(u)
    return 0.5f * x * (1.0f + t);
}

__device__ __forceinline__ short f2bf(float f) {   // round-to-nearest-even bf16
    unsigned int u = __float_as_uint(f);
    unsigned int r = u + 0x7FFFu + ((u >> 16) & 1u);
    return (short)(r >> 16);
}

// ---------------- prep: transpose-convert weights to bf16 [N][K] ----------------
__global__ __launch_bounds__(256) void prep_weights_kernel(
    const float* __restrict__ We1, const float* __restrict__ We2,
    short* __restrict__ We1T, short* __restrict__ We2T)
{
    int idx = blockIdx.x * 256 + threadIdx.x;
    if (idx < 128 * 512) {           // We1T[n][k] = bf16(We1[k][n])
        int n = idx >> 9, k = idx & 511;
        We1T[idx] = f2bf(We1[k * HH + n]);
    } else {
        int j = idx - 128 * 512;
        if (j < 64 * 128) {          // We2T[n][k] = bf16(We2[k][n])
            int n = j >> 7, k = j & 127;
            We2T[j] = f2bf(We2[k * RR + n]);
        }
    }
}

// ---------------- Kernel A: add path (512 rows, tiny, fp32) ----------------
__global__ __launch_bounds__(256) void add_path_kernel(
    const float* __restrict__ ot, const float* __restrict__ scale,
    const float* __restrict__ bias, const float* __restrict__ Wa1,
    const float* __restrict__ ba1, const float* __restrict__ Wa2,
    const float* __restrict__ ba2, float* __restrict__ add_out)
{
    int tid = threadIdx.x;
    int b = blockIdx.x >> 6, r = blockIdx.x & 63;
    const float* x = ot + (size_t)(b * RR + r) * DD;
    __shared__ float xs[DD];
    __shared__ float hsm[HH];
    __shared__ float rs[4], rq[4];
    float v0 = x[tid], v1 = x[tid + 256];
    float s = v0 + v1, q = v0 * v0 + v1 * v1;
    #pragma unroll
    for (int off = 32; off > 0; off >>= 1) { s += __shfl_xor(s, off); q += __shfl_xor(q, off); }
    if ((tid & 63) == 0) { rs[tid >> 6] = s; rq[tid >> 6] = q; }
    __syncthreads();
    s = rs[0] + rs[1] + rs[2] + rs[3];
    q = rq[0] + rq[1] + rq[2] + rq[3];
    float mean = s * (1.0f / DD);
    float var = q * (1.0f / DD) - mean * mean;
    float inv = rsqrtf(var + 1e-6f);
    xs[tid]       = (v0 - mean) * inv * scale[tid]       + bias[tid];
    xs[tid + 256] = (v1 - mean) * inv * scale[tid + 256] + bias[tid + 256];
    __syncthreads();
    if (tid < HH) {
        float acc = ba1[tid];
        for (int k = 0; k < DD; k++) acc = fmaf(xs[k], Wa1[k * HH + tid], acc);
        hsm[tid] = gelu_tanh(acc);
    }
    __syncthreads();
    int d0 = tid, d1 = tid + 256;
    float a0 = ba2[d0], a1 = ba2[d1];
    #pragma unroll 4
    for (int k = 0; k < HH; k++) {
        float hk = hsm[k];
        a0 = fmaf(hk, Wa2[k * DD + d0], a0);
        a1 = fmaf(hk, Wa2[k * DD + d1], a1);
    }
    add_out[(size_t)(b * RR + r) * DD + d0] = a0;
    add_out[(size_t)(b * RR + r) * DD + d1] = a1;
}

// ---------------- erase path: LN + bf16 MFMA GEMM1 + gelu + MFMA GEMM2 + partial softmax
// Block = 32 memory rows, 256 threads (4 waves). Waves tile GEMM1 as 2M x 2N.
__global__ __launch_bounds__(256) void erase_mfma_kernel(
    const float* __restrict__ mem, const float* __restrict__ scale,
    const float* __restrict__ bias, const short* __restrict__ We1T,
    const float* __restrict__ be1, const short* __restrict__ We2T,
    const float* __restrict__ be2, float* __restrict__ logits,
    float* __restrict__ pmax, float* __restrict__ psum)
{
    __shared__ short xn[32 * XN_LD];     // 33,280 B
    __shared__ short hsm[32 * H_LD];     //  8,704 B
    __shared__ float pml[2][64], psl[2][64];

    int tid = threadIdx.x;
    int w = tid >> 6, l = tid & 63;
    int b = blockIdx.x >> 8;
    int chunk = blockIdx.x & 255;
    int m0 = chunk * 32;
    const float* src = mem + (size_t)(b * MM + m0) * DD;

    // ---- LN: wave w handles rows w*8 .. w*8+7; lane covers cols l*8..+7 ----
    float4 sc0 = *(const float4*)(scale + l * 8);
    float4 sc1 = *(const float4*)(scale + l * 8 + 4);
    float4 bi0 = *(const float4*)(bias + l * 8);
    float4 bi1 = *(const float4*)(bias + l * 8 + 4);
    for (int i = 0; i < 8; i++) {
        int row = w * 8 + i;
        const float* xr = src + (size_t)row * DD + l * 8;
        float4 v0 = *(const float4*)xr;
        float4 v1 = *(const float4*)(xr + 4);
        float s = v0.x + v0.y + v0.z + v0.w + v1.x + v1.y + v1.z + v1.w;
        float q = v0.x*v0.x + v0.y*v0.y + v0.z*v0.z + v0.w*v0.w
                + v1.x*v1.x + v1.y*v1.y + v1.z*v1.z + v1.w*v1.w;
        #pragma unroll
        for (int off = 32; off > 0; off >>= 1) { s += __shfl_xor(s, off); q += __shfl_xor(q, off); }
        float mean = s * (1.0f / 512.0f);
        float var = q * (1.0f / 512.0f) - mean * mean;
        float inv = rsqrtf(var + 1e-6f);
        bf16x8 o;
        o[0] = f2bf((v0.x - mean) * inv * sc0.x + bi0.x);
        o[1] = f2bf((v0.y - mean) * inv * sc0.y + bi0.y);
        o[2] = f2bf((v0.z - mean) * inv * sc0.z + bi0.z);
        o[3] = f2bf((v0.w - mean) * inv * sc0.w + bi0.w);
        o[4] = f2bf((v1.x - mean) * inv * sc1.x + bi1.x);
        o[5] = f2bf((v1.y - mean) * inv * sc1.y + bi1.y);
        o[6] = f2bf((v1.z - mean) * inv * sc1.z + bi1.z);
        o[7] = f2bf((v1.w - mean) * inv * sc1.w + bi1.w);
        *(bf16x8*)&xn[row * XN_LD + l * 8] = o;
    }
    __syncthreads();

    // ---- GEMM1: [32 x 512] x [512 x 128] -> acc (wave: 16 rows x 64 cols) ----
    int wm = w >> 1, wn = w & 1;
    int lr = l & 15, kg = (l >> 4) * 8;
    int arow = wm * 16 + lr;
    f32x4 acc[4];
    #pragma unroll
    for (int nf = 0; nf < 4; nf++) acc[nf] = (f32x4){0.f, 0.f, 0.f, 0.f};
    #pragma unroll 4
    for (int ks = 0; ks < 16; ks++) {
        int k0 = ks * 32;
        bf16x8 a = *(const bf16x8*)&xn[arow * XN_LD + k0 + kg];
        #pragma unroll
        for (int nf = 0; nf < 4; nf++) {
            int col = wn * 64 + nf * 16 + lr;
            bf16x8 bfr = *(const bf16x8*)&We1T[(size_t)col * 512 + k0 + kg];
            acc[nf] = __builtin_amdgcn_mfma_f32_16x16x32_bf16(a, bfr, acc[nf], 0, 0, 0);
        }
    }
    // epilogue: +bias, gelu, bf16 -> hsm
    #pragma unroll
    for (int nf = 0; nf < 4; nf++) {
        int col = wn * 64 + nf * 16 + lr;
        float bv = be1[col];
        #pragma unroll
        for (int rg = 0; rg < 4; rg++) {
            int row = wm * 16 + (l >> 4) * 4 + rg;
            hsm[row * H_LD + col] = f2bf(gelu_tanh(acc[nf][rg] + bv));
        }
    }
    __syncthreads();

    // ---- GEMM2: [32 x 128] x [128 x 64] -> logits tile (wave: 16 rows x 32 cols) ----
    int wm2 = w >> 1, nb2 = (w & 1) * 32;
    int arow2 = wm2 * 16 + lr;
    f32x4 acc2[2];
    acc2[0] = (f32x4){0.f, 0.f, 0.f, 0.f};
    acc2[1] = (f32x4){0.f, 0.f, 0.f, 0.f};
    #pragma unroll
    for (int ks = 0; ks < 4; ks++) {
        int k0 = ks * 32;
        bf16x8 a = *(const bf16x8*)&hsm[arow2 * H_LD + k0 + kg];
        #pragma unroll
        for (int nf = 0; nf < 2; nf++) {
            int col = nb2 + nf * 16 + lr;
            bf16x8 bfr = *(const bf16x8*)&We2T[col * 128 + k0 + kg];
            acc2[nf] = __builtin_amdgcn_mfma_f32_16x16x32_bf16(a, bfr, acc2[nf], 0, 0, 0);
        }
    }
    // ---- +bias, store logits, per-column online (max, sumexp) over this block's rows
    #pragma unroll
    for (int nf = 0; nf < 2; nf++) {
        int col = nb2 + nf * 16 + lr;
        float bv = be2[col];
        float v[4];
        #pragma unroll
        for (int rg = 0; rg < 4; rg++) {
            int row = wm2 * 16 + (l >> 4) * 4 + rg;
            v[rg] = acc2[nf][rg] + bv;
            logits[(size_t)(b * MM + m0 + row) * 64 + col] = v[rg];
        }
        float mx = fmaxf(fmaxf(v[0], v[1]), fmaxf(v[2], v[3]));
        float sm = __expf(v[0] - mx) + __expf(v[1] - mx) + __expf(v[2] - mx) + __expf(v[3] - mx);
        #pragma unroll
        for (int off = 16; off <= 32; off <<= 1) {
            float om = __shfl_xor(mx, off);
            float os = __shfl_xor(sm, off);
            float nm = fmaxf(mx, om);
            sm = sm * __expf(mx - nm) + os * __expf(om - nm);
            mx = nm;
        }
        if ((l >> 4) == 0) { pml[wm2][col] = mx; psl[wm2][col] = sm; }
    }
    __syncthreads();
    if (tid < 64) {
        float m0_ = pml[0][tid], s0_ = psl[0][tid];
        float m1_ = pml[1][tid], s1_ = psl[1][tid];
        float nm = fmaxf(m0_, m1_);
        float S  = s0_ * __expf(m0_ - nm) + s1_ * __expf(m1_ - nm);
        pmax[((size_t)b * 256 + chunk) * 64 + tid] = nm;
        psum[((size_t)b * 256 + chunk) * 64 + tid] = S;
    }
}

// ---------------- combine 256 chunk partials -> rmax, rinv ------------------
__global__ __launch_bounds__(256) void softmax_finalize_kernel(
    const float* __restrict__ pmax, const float* __restrict__ psum,
    float* __restrict__ rmax, float* __restrict__ rinv)
{
    int b = blockIdx.x;
    int g = threadIdx.x >> 6, r = threadIdx.x & 63;
    float mx = -1e30f, sm = 0.0f;
    for (int ch = g; ch < 256; ch += 4) {
        float m2 = pmax[((size_t)b * 256 + ch) * 64 + r];
        float s2 = psum[((size_t)b * 256 + ch) * 64 + r];
        float nm = fmaxf(mx, m2);
        sm = sm * __expf(mx - nm) + s2 * __expf(m2 - nm);
        mx = nm;
    }
    __shared__ float sx_[4][64], sm_[4][64];
    sx_[g][r] = mx; sm_[g][r] = sm;
    __syncthreads();
    if (threadIdx.x < 64) {
        float M_ = sx_[0][threadIdx.x], S_ = sm_[0][threadIdx.x];
        #pragma unroll
        for (int gg = 1; gg < 4; gg++) {
            float m2 = sx_[gg][threadIdx.x], s2 = sm_[gg][threadIdx.x];
            float nm = fmaxf(M_, m2);
            S_ = S_ * __expf(M_ - nm) + s2 * __expf(m2 - nm);
            M_ = nm;
        }
        rmax[b * 64 + threadIdx.x] = M_;
        rinv[b * 64 + threadIdx.x] = 1.0f / S_;
    }
}

// ---------------- apply: ea = softmax_w @ add; out = mem + ea*(1-mem) --------
__global__ __launch_bounds__(256) void apply_kernel(
    const float* __restrict__ mem, const float* __restrict__ logits,
    const float* __restrict__ add, const float* __restrict__ rmax,
    const float* __restrict__ rinv, float* __restrict__ out)
{
    extern __shared__ float lds[];
    float* addl  = lds;                 // 64*512
    float* wlds  = lds + 64 * 512;      // 16*64
    float* rmaxl = wlds + 16 * 64;      // 64
    float* rinvl = rmaxl + 64;          // 64
    int tid = threadIdx.x;
    int b = blockIdx.x >> 6, mt = blockIdx.x & 63;
    int m0 = mt * 128;
    const float* asrc = add + (size_t)b * RR * DD;
    for (int idx = tid; idx < RR * DD; idx += 256) addl[idx] = asrc[idx];
    if (tid < 64) { rmaxl[tid] = rmax[b * 64 + tid]; rinvl[tid] = rinv[b * 64 + tid]; }
    __syncthreads();
    int rg = tid >> 7, c = tid & 127;
    for (int p = 0; p < 8; p++) {
        int mp = m0 + p * 16;
        #pragma unroll
        for (int i = 0; i < 4; i++) {
            int fl = tid + 256 * i;
            int row = fl >> 6, r = fl & 63;
            float w = __expf(logits[((size_t)(b * MM + mp + row)) * 64 + r] - rmaxl[r]) * rinvl[r];
            wlds[row * 64 + r] = w;
        }
        __syncthreads();
        float4 acc[8];
        #pragma unroll
        for (int i = 0; i < 8; i++) acc[i] = make_float4(0.f, 0.f, 0.f, 0.f);
        for (int r = 0; r < 64; r++) {
            float4 a4 = *(const float4*)&addl[r * 512 + c * 4];
            #pragma unroll
            for (int i = 0; i < 8; i++) {
                float w = wlds[(rg * 8 + i) * 64 + r];
                acc[i].x = fmaf(w, a4.x, acc[i].x);
                acc[i].y = fmaf(w, a4.y, acc[i].y);
                acc[i].z = fmaf(w, a4.z, acc[i].z);
                acc[i].w = fmaf(w, a4.w, acc[i].w);
            }
        }
        #pragma unroll
        for (int i = 0; i < 8; i++) {
            int m = mp + rg * 8 + i;
            float4 mv = *(const float4*)&mem[((size_t)(b * MM + m)) * DD + c * 4];
            float4 o;
            o.x = fmaf(acc[i].x, 1.0f - mv.x, mv.x);
            o.y = fmaf(acc[i].y, 1.0f - mv.y, mv.y);
            o.z = fmaf(acc[i].z, 1.0f - mv.z, mv.z);
            o.w = fmaf(acc[i].w, 1.0f - mv.w, mv.w);
            *(float4*)&out[((size_t)(b * MM + m)) * DD + c * 4] = o;
        }
        __syncthreads();
    }
}

extern "C" void kernel_launch(void* const* d_in, const int* in_sizes, int n_in,
                              void* d_out, int out_size, void* d_ws, size_t ws_size,
                              hipStream_t stream) {
    const float* memory = (const float*)d_in[0];
    const float* ot     = (const float*)d_in[1];
    const float* ln_e_s = (const float*)d_in[2];
    const float* ln_e_b = (const float*)d_in[3];
    const float* We1    = (const float*)d_in[4];
    const float* be1    = (const float*)d_in[5];
    const float* We2    = (const float*)d_in[6];
    const float* be2    = (const float*)d_in[7];
    const float* ln_a_s = (const float*)d_in[8];
    const float* ln_a_b = (const float*)d_in[9];
    const float* Wa1    = (const float*)d_in[10];
    const float* ba1    = (const float*)d_in[11];
    const float* Wa2    = (const float*)d_in[12];
    const float* ba2    = (const float*)d_in[13];
    float* out = (float*)d_out;

    float* ws      = (float*)d_ws;
    float* add_ws  = ws;                         // 262,144 floats
    float* logits  = ws + 262144;                // 4,194,304 floats
    float* pmaxw   = ws + 262144 + 4194304;      // 131,072 floats (8*256*64)
    float* psumw   = pmaxw + 131072;             // 131,072
    float* rmaxw   = psumw + 131072;             // 512
    float* rinvw   = rmaxw + 512;                // 512
    short* We1T    = (short*)(rinvw + 512);      // 65,536 bf16
    short* We2T    = We1T + 128 * 512;           // 8,192 bf16

    hipLaunchKernelGGL(prep_weights_kernel, dim3(288), dim3(256), 0, stream,
                       We1, We2, We1T, We2T);
    hipLaunchKernelGGL(add_path_kernel, dim3(BB * RR), dim3(256), 0, stream,
                       ot, ln_a_s, ln_a_b, Wa1, ba1, Wa2, ba2, add_ws);
    hipLaunchKernelGGL(erase_mfma_kernel, dim3(BB * 256), dim3(256), 0, stream,
                       memory, ln_e_s, ln_e_b, We1T, be1, We2T, be2, logits, pmaxw, psumw);
    hipLaunchKernelGGL(softmax_finalize_kernel, dim3(BB), dim3(256), 0, stream,
                       pmaxw, psumw, rmaxw, rinvw);

    size_t k4_lds = (size_t)(64 * 512 + 16 * 64 + 128) * sizeof(float); // 135,680 B
    hipFuncSetAttribute((const void*)apply_kernel,
                        hipFuncAttributeMaxDynamicSharedMemorySize, (int)k4_lds);
    hipLaunchKernelGGL(apply_kernel, dim3(BB * 64), dim3(256), k4_lds, stream,
                       memory, logits, add_ws, rmaxw, rinvw, out);
}

// Round 3
// 251.147 us; speedup vs baseline: 1.6706x; 1.0833x over previous
//
#include <hip/hip_runtime.h>
#include <hip/hip_bf16.h>
#include <math.h>

#define BB 8
#define MM 8192
#define DD 512
#define RR 64
#define HH 128

typedef __attribute__((ext_vector_type(8))) short bf16x8;
typedef __attribute__((ext_vector_type(4))) float f32x4;

#define XN_LD 520   // bf16 elems per xn row (512 + 8 pad -> 1040B stride, 16B aligned)
#define H_LD  136   // bf16 elems per h row  (128 + 8 pad -> 272B stride, 16B aligned)

__device__ __forceinline__ float gelu_tanh(float x) {
    float u = 0.7978845608028654f * (x + 0.044715f * x * x * x);
    float e = __expf(2.0f * u);
    float t = 1.0f - 2.0f / (e + 1.0f);   // tanh(u)
    return 0.5f * x * (1.0f + t);
}

__device__ __forceinline__ short f2bf(float f) {   // round-to-nearest-even bf16
    unsigned int u = __float_as_uint(f);
    unsigned int r = u + 0x7FFFu + ((u >> 16) & 1u);
    return (short)(r >> 16);
}

// ---------------- prep: transpose-convert weights to bf16 [N][K] ----------------
__global__ __launch_bounds__(256) void prep_weights_kernel(
    const float* __restrict__ We1, const float* __restrict__ We2,
    short* __restrict__ We1T, short* __restrict__ We2T)
{
    int idx = blockIdx.x * 256 + threadIdx.x;
    if (idx < 128 * 512) {           // We1T[n][k] = bf16(We1[k][n])
        int n = idx >> 9, k = idx & 511;
        We1T[idx] = f2bf(We1[k * HH + n]);
    } else {
        int j = idx - 128 * 512;
        if (j < 64 * 128) {          // We2T[n][k] = bf16(We2[k][n])
            int n = j >> 7, k = j & 127;
            We2T[j] = f2bf(We2[k * RR + n]);
        }
    }
}

// ---------------- Kernel A: add path (512 rows, tiny, fp32) ----------------
__global__ __launch_bounds__(256) void add_path_kernel(
    const float* __restrict__ ot, const float* __restrict__ scale,
    const float* __restrict__ bias, const float* __restrict__ Wa1,
    const float* __restrict__ ba1, const float* __restrict__ Wa2,
    const float* __restrict__ ba2, float* __restrict__ add_out)
{
    int tid = threadIdx.x;
    int b = blockIdx.x >> 6, r = blockIdx.x & 63;
    const float* x = ot + (size_t)(b * RR + r) * DD;
    __shared__ float xs[DD];
    __shared__ float hsm[HH];
    __shared__ float rs[4], rq[4];
    float v0 = x[tid], v1 = x[tid + 256];
    float s = v0 + v1, q = v0 * v0 + v1 * v1;
    #pragma unroll
    for (int off = 32; off > 0; off >>= 1) { s += __shfl_xor(s, off); q += __shfl_xor(q, off); }
    if ((tid & 63) == 0) { rs[tid >> 6] = s; rq[tid >> 6] = q; }
    __syncthreads();
    s = rs[0] + rs[1] + rs[2] + rs[3];
    q = rq[0] + rq[1] + rq[2] + rq[3];
    float mean = s * (1.0f / DD);
    float var = q * (1.0f / DD) - mean * mean;
    float inv = rsqrtf(var + 1e-6f);
    xs[tid]       = (v0 - mean) * inv * scale[tid]       + bias[tid];
    xs[tid + 256] = (v1 - mean) * inv * scale[tid + 256] + bias[tid + 256];
    __syncthreads();
    if (tid < HH) {
        float acc = ba1[tid];
        for (int k = 0; k < DD; k++) acc = fmaf(xs[k], Wa1[k * HH + tid], acc);
        hsm[tid] = gelu_tanh(acc);
    }
    __syncthreads();
    int d0 = tid, d1 = tid + 256;
    float a0 = ba2[d0], a1 = ba2[d1];
    #pragma unroll 4
    for (int k = 0; k < HH; k++) {
        float hk = hsm[k];
        a0 = fmaf(hk, Wa2[k * DD + d0], a0);
        a1 = fmaf(hk, Wa2[k * DD + d1], a1);
    }
    add_out[(size_t)(b * RR + r) * DD + d0] = a0;
    add_out[(size_t)(b * RR + r) * DD + d1] = a1;
}

// ---------------- erase path: LN + bf16 MFMA GEMM1 + gelu + MFMA GEMM2 + partial softmax
__global__ __launch_bounds__(256) void erase_mfma_kernel(
    const float* __restrict__ mem, const float* __restrict__ scale,
    const float* __restrict__ bias, const short* __restrict__ We1T,
    const float* __restrict__ be1, const short* __restrict__ We2T,
    const float* __restrict__ be2, float* __restrict__ logits,
    float* __restrict__ pmax, float* __restrict__ psum)
{
    __shared__ short xn[32 * XN_LD];     // 33,280 B
    __shared__ short hsm[32 * H_LD];     //  8,704 B
    __shared__ float pml[2][64], psl[2][64];

    int tid = threadIdx.x;
    int w = tid >> 6, l = tid & 63;
    int b = blockIdx.x >> 8;
    int chunk = blockIdx.x & 255;
    int m0 = chunk * 32;
    const float* src = mem + (size_t)(b * MM + m0) * DD;

    // ---- LN: wave w handles rows w*8 .. w*8+7; lane covers cols l*8..+7 ----
    float4 sc0 = *(const float4*)(scale + l * 8);
    float4 sc1 = *(const float4*)(scale + l * 8 + 4);
    float4 bi0 = *(const float4*)(bias + l * 8);
    float4 bi1 = *(const float4*)(bias + l * 8 + 4);
    for (int i = 0; i < 8; i++) {
        int row = w * 8 + i;
        const float* xr = src + (size_t)row * DD + l * 8;
        float4 v0 = *(const float4*)xr;
        float4 v1 = *(const float4*)(xr + 4);
        float s = v0.x + v0.y + v0.z + v0.w + v1.x + v1.y + v1.z + v1.w;
        float q = v0.x*v0.x + v0.y*v0.y + v0.z*v0.z + v0.w*v0.w
                + v1.x*v1.x + v1.y*v1.y + v1.z*v1.z + v1.w*v1.w;
        #pragma unroll
        for (int off = 32; off > 0; off >>= 1) { s += __shfl_xor(s, off); q += __shfl_xor(q, off); }
        float mean = s * (1.0f / 512.0f);
        float var = q * (1.0f / 512.0f) - mean * mean;
        float inv = rsqrtf(var + 1e-6f);
        bf16x8 o;
        o[0] = f2bf((v0.x - mean) * inv * sc0.x + bi0.x);
        o[1] = f2bf((v0.y - mean) * inv * sc0.y + bi0.y);
        o[2] = f2bf((v0.z - mean) * inv * sc0.z + bi0.z);
        o[3] = f2bf((v0.w - mean) * inv * sc0.w + bi0.w);
        o[4] = f2bf((v1.x - mean) * inv * sc1.x + bi1.x);
        o[5] = f2bf((v1.y - mean) * inv * sc1.y + bi1.y);
        o[6] = f2bf((v1.z - mean) * inv * sc1.z + bi1.z);
        o[7] = f2bf((v1.w - mean) * inv * sc1.w + bi1.w);
        *(bf16x8*)&xn[row * XN_LD + l * 8] = o;
    }
    __syncthreads();

    // ---- GEMM1: [32 x 512] x [512 x 128] ----
    int wm = w >> 1, wn = w & 1;
    int lr = l & 15, kg = (l >> 4) * 8;
    int arow = wm * 16 + lr;
    f32x4 acc[4];
    #pragma unroll
    for (int nf = 0; nf < 4; nf++) acc[nf] = (f32x4){0.f, 0.f, 0.f, 0.f};
    #pragma unroll 4
    for (int ks = 0; ks < 16; ks++) {
        int k0 = ks * 32;
        bf16x8 a = *(const bf16x8*)&xn[arow * XN_LD + k0 + kg];
        #pragma unroll
        for (int nf = 0; nf < 4; nf++) {
            int col = wn * 64 + nf * 16 + lr;
            bf16x8 bfr = *(const bf16x8*)&We1T[(size_t)col * 512 + k0 + kg];
            acc[nf] = __builtin_amdgcn_mfma_f32_16x16x32_bf16(a, bfr, acc[nf], 0, 0, 0);
        }
    }
    #pragma unroll
    for (int nf = 0; nf < 4; nf++) {
        int col = wn * 64 + nf * 16 + lr;
        float bv = be1[col];
        #pragma unroll
        for (int rg = 0; rg < 4; rg++) {
            int row = wm * 16 + (l >> 4) * 4 + rg;
            hsm[row * H_LD + col] = f2bf(gelu_tanh(acc[nf][rg] + bv));
        }
    }
    __syncthreads();

    // ---- GEMM2: [32 x 128] x [128 x 64] ----
    int wm2 = w >> 1, nb2 = (w & 1) * 32;
    int arow2 = wm2 * 16 + lr;
    f32x4 acc2[2];
    acc2[0] = (f32x4){0.f, 0.f, 0.f, 0.f};
    acc2[1] = (f32x4){0.f, 0.f, 0.f, 0.f};
    #pragma unroll
    for (int ks = 0; ks < 4; ks++) {
        int k0 = ks * 32;
        bf16x8 a = *(const bf16x8*)&hsm[arow2 * H_LD + k0 + kg];
        #pragma unroll
        for (int nf = 0; nf < 2; nf++) {
            int col = nb2 + nf * 16 + lr;
            bf16x8 bfr = *(const bf16x8*)&We2T[col * 128 + k0 + kg];
            acc2[nf] = __builtin_amdgcn_mfma_f32_16x16x32_bf16(a, bfr, acc2[nf], 0, 0, 0);
        }
    }
    #pragma unroll
    for (int nf = 0; nf < 2; nf++) {
        int col = nb2 + nf * 16 + lr;
        float bv = be2[col];
        float v[4];
        #pragma unroll
        for (int rg = 0; rg < 4; rg++) {
            int row = wm2 * 16 + (l >> 4) * 4 + rg;
            v[rg] = acc2[nf][rg] + bv;
            logits[(size_t)(b * MM + m0 + row) * 64 + col] = v[rg];
        }
        float mx = fmaxf(fmaxf(v[0], v[1]), fmaxf(v[2], v[3]));
        float sm = __expf(v[0] - mx) + __expf(v[1] - mx) + __expf(v[2] - mx) + __expf(v[3] - mx);
        #pragma unroll
        for (int off = 16; off <= 32; off <<= 1) {
            float om = __shfl_xor(mx, off);
            float os = __shfl_xor(sm, off);
            float nm = fmaxf(mx, om);
            sm = sm * __expf(mx - nm) + os * __expf(om - nm);
            mx = nm;
        }
        if ((l >> 4) == 0) { pml[wm2][col] = mx; psl[wm2][col] = sm; }
    }
    __syncthreads();
    if (tid < 64) {
        float m0_ = pml[0][tid], s0_ = psl[0][tid];
        float m1_ = pml[1][tid], s1_ = psl[1][tid];
        float nm = fmaxf(m0_, m1_);
        float S  = s0_ * __expf(m0_ - nm) + s1_ * __expf(m1_ - nm);
        pmax[((size_t)b * 256 + chunk) * 64 + tid] = nm;
        psum[((size_t)b * 256 + chunk) * 64 + tid] = S;
    }
}

// ---------------- combine 256 chunk partials -> rmax, rinv ------------------
__global__ __launch_bounds__(256) void softmax_finalize_kernel(
    const float* __restrict__ pmax, const float* __restrict__ psum,
    float* __restrict__ rmax, float* __restrict__ rinv)
{
    int b = blockIdx.x;
    int g = threadIdx.x >> 6, r = threadIdx.x & 63;
    float mx = -1e30f, sm = 0.0f;
    for (int ch = g; ch < 256; ch += 4) {
        float m2 = pmax[((size_t)b * 256 + ch) * 64 + r];
        float s2 = psum[((size_t)b * 256 + ch) * 64 + r];
        float nm = fmaxf(mx, m2);
        sm = sm * __expf(mx - nm) + s2 * __expf(m2 - nm);
        mx = nm;
    }
    __shared__ float sx_[4][64], sm_[4][64];
    sx_[g][r] = mx; sm_[g][r] = sm;
    __syncthreads();
    if (threadIdx.x < 64) {
        float M_ = sx_[0][threadIdx.x], S_ = sm_[0][threadIdx.x];
        #pragma unroll
        for (int gg = 1; gg < 4; gg++) {
            float m2 = sx_[gg][threadIdx.x], s2 = sm_[gg][threadIdx.x];
            float nm = fmaxf(M_, m2);
            S_ = S_ * __expf(M_ - nm) + s2 * __expf(m2 - nm);
            M_ = nm;
        }
        rmax[b * 64 + threadIdx.x] = M_;
        rinv[b * 64 + threadIdx.x] = 1.0f / S_;
    }
}

// ---------------- scale+transpose add -> addT[b][d][r] bf16 (rinv folded in) ----------
__global__ __launch_bounds__(256) void scale_transpose_kernel(
    const float* __restrict__ add, const float* __restrict__ rinv,
    short* __restrict__ addT)
{
    int b = blockIdx.x;
    int t = threadIdx.x;
    const float* rv = rinv + b * 64;
    for (int i = 0; i < 128; i++) {
        int idx = t + i * 256;           // 0 .. 32767
        int d = idx >> 6, r = idx & 63;
        addT[(size_t)b * 32768 + idx] =
            f2bf(add[((size_t)b * 64 + r) * 512 + d] * rv[r]);
    }
}

// ---------------- apply: ea = exp(logit-rmax) @ addT (MFMA); out = mem + ea*(1-mem) ----
// Block = 64 m-rows x 512 d. 4 waves, wave w owns d in [w*128, w*128+128). No LDS.
__global__ __launch_bounds__(256, 4) void apply_mfma_kernel(
    const float* __restrict__ mem, const float* __restrict__ logits,
    const short* __restrict__ addT, const float* __restrict__ rmax,
    float* __restrict__ out)
{
    int tid = threadIdx.x;
    int w = tid >> 6, l = tid & 63;
    int b = blockIdx.x >> 7;
    int mt = blockIdx.x & 127;
    int m0 = mt * 64;
    int lr = l & 15, kg = (l >> 4) * 8;
    int nbase = w * 128;
    const short* aT = addT + (size_t)b * 512 * 64;

    // per-lane rmax for its 16 r-slots (k0=0 and k0=32)
    float rm0[8], rm1[8];
    #pragma unroll
    for (int j = 0; j < 8; j++) {
        rm0[j] = rmax[b * 64 + kg + j];
        rm1[j] = rmax[b * 64 + 32 + kg + j];
    }

    for (int ms = 0; ms < 4; ms++) {
        int mrow = m0 + ms * 16 + lr;
        const float* lp = logits + (size_t)(b * MM + mrow) * 64 + kg;
        float w0[8], w1[8];
        #pragma unroll
        for (int j = 0; j < 8; j++) {
            w0[j] = __expf(lp[j]      - rm0[j]);
            w1[j] = __expf(lp[32 + j] - rm1[j]);
        }
        bf16x8 a0, a1;
        #pragma unroll
        for (int j = 0; j < 8; j++) { a0[j] = f2bf(w0[j]); a1[j] = f2bf(w1[j]); }

        f32x4 acc[8];
        #pragma unroll
        for (int nf = 0; nf < 8; nf++) {
            int d = nbase + nf * 16 + lr;
            bf16x8 b0 = *(const bf16x8*)&aT[d * 64 + kg];
            bf16x8 b1 = *(const bf16x8*)&aT[d * 64 + 32 + kg];
            f32x4 c = (f32x4){0.f, 0.f, 0.f, 0.f};
            c = __builtin_amdgcn_mfma_f32_16x16x32_bf16(a0, b0, c, 0, 0, 0);
            c = __builtin_amdgcn_mfma_f32_16x16x32_bf16(a1, b1, c, 0, 0, 0);
            acc[nf] = c;
        }
        // epilogue: out = mem + ea*(1-mem)
        #pragma unroll
        for (int nf = 0; nf < 8; nf++) {
            int d = nbase + nf * 16 + lr;
            #pragma unroll
            for (int rg = 0; rg < 4; rg++) {
                int m = m0 + ms * 16 + (l >> 4) * 4 + rg;
                size_t off = (size_t)(b * MM + m) * DD + d;
                float mv = mem[off];
                out[off] = fmaf(acc[nf][rg], 1.0f - mv, mv);
            }
        }
    }
}

extern "C" void kernel_launch(void* const* d_in, const int* in_sizes, int n_in,
                              void* d_out, int out_size, void* d_ws, size_t ws_size,
                              hipStream_t stream) {
    const float* memory = (const float*)d_in[0];
    const float* ot     = (const float*)d_in[1];
    const float* ln_e_s = (const float*)d_in[2];
    const float* ln_e_b = (const float*)d_in[3];
    const float* We1    = (const float*)d_in[4];
    const float* be1    = (const float*)d_in[5];
    const float* We2    = (const float*)d_in[6];
    const float* be2    = (const float*)d_in[7];
    const float* ln_a_s = (const float*)d_in[8];
    const float* ln_a_b = (const float*)d_in[9];
    const float* Wa1    = (const float*)d_in[10];
    const float* ba1    = (const float*)d_in[11];
    const float* Wa2    = (const float*)d_in[12];
    const float* ba2    = (const float*)d_in[13];
    float* out = (float*)d_out;

    float* ws      = (float*)d_ws;
    float* add_ws  = ws;                         // 262,144 floats
    float* logits  = ws + 262144;                // 4,194,304 floats
    float* pmaxw   = ws + 262144 + 4194304;      // 131,072 floats
    float* psumw   = pmaxw + 131072;             // 131,072
    float* rmaxw   = psumw + 131072;             // 512
    float* rinvw   = rmaxw + 512;                // 512
    short* We1T    = (short*)(rinvw + 512);      // 65,536 bf16
    short* We2T    = We1T + 128 * 512;           // 8,192 bf16
    short* addT    = We2T + 64 * 128;            // 262,144 bf16

    hipLaunchKernelGGL(prep_weights_kernel, dim3(288), dim3(256), 0, stream,
                       We1, We2, We1T, We2T);
    hipLaunchKernelGGL(add_path_kernel, dim3(BB * RR), dim3(256), 0, stream,
                       ot, ln_a_s, ln_a_b, Wa1, ba1, Wa2, ba2, add_ws);
    hipLaunchKernelGGL(erase_mfma_kernel, dim3(BB * 256), dim3(256), 0, stream,
                       memory, ln_e_s, ln_e_b, We1T, be1, We2T, be2, logits, pmaxw, psumw);
    hipLaunchKernelGGL(softmax_finalize_kernel, dim3(BB), dim3(256), 0, stream,
                       pmaxw, psumw, rmaxw, rinvw);
    hipLaunchKernelGGL(scale_transpose_kernel, dim3(BB), dim3(256), 0, stream,
                       add_ws, rinvw, addT);
    hipLaunchKernelGGL(apply_mfma_kernel, dim3(BB * 128), dim3(256), 0, stream,
                       memory, logits, addT, rmaxw, out);
}

// Round 5
// 222.098 us; speedup vs baseline: 1.8891x; 1.1308x over previous
//
#include <hip/hip_runtime.h>
#include <hip/hip_bf16.h>
#include <math.h>

#define BB 8
#define MM 8192
#define DD 512
#define RR 64
#define HH 128

typedef __attribute__((ext_vector_type(8))) short bf16x8;
typedef __attribute__((ext_vector_type(4))) short bf16x4;
typedef __attribute__((ext_vector_type(4))) float f32x4;

#define XN_LD 520   // bf16 elems per xn row (512 + 8 pad)
#define H_LD  136   // bf16 elems per h row  (128 + 8 pad)

__device__ __forceinline__ float gelu_tanh(float x) {
    float u = 0.7978845608028654f * (x + 0.044715f * x * x * x);
    float e = __expf(2.0f * u);
    float t = 1.0f - 2.0f / (e + 1.0f);   // tanh(u)
    return 0.5f * x * (1.0f + t);
}

__device__ __forceinline__ short f2bf(float f) {   // round-to-nearest-even bf16
    unsigned int u = __float_as_uint(f);
    unsigned int r = u + 0x7FFFu + ((u >> 16) & 1u);
    return (short)(r >> 16);
}

// ---------------- prep: transpose-convert weights to bf16 [N][K] ----------------
__global__ __launch_bounds__(256) void prep_weights_kernel(
    const float* __restrict__ We1, const float* __restrict__ We2,
    short* __restrict__ We1T, short* __restrict__ We2T)
{
    int idx = blockIdx.x * 256 + threadIdx.x;
    if (idx < 128 * 512) {           // We1T[n][k] = bf16(We1[k][n])
        int n = idx >> 9, k = idx & 511;
        We1T[idx] = f2bf(We1[k * HH + n]);
    } else {
        int j = idx - 128 * 512;
        if (j < 64 * 128) {          // We2T[n][k] = bf16(We2[k][n])
            int n = j >> 7, k = j & 127;
            We2T[j] = f2bf(We2[k * RR + n]);
        }
    }
}

// ---------------- Kernel A: add path (512 rows, tiny, fp32) ----------------
__global__ __launch_bounds__(256) void add_path_kernel(
    const float* __restrict__ ot, const float* __restrict__ scale,
    const float* __restrict__ bias, const float* __restrict__ Wa1,
    const float* __restrict__ ba1, const float* __restrict__ Wa2,
    const float* __restrict__ ba2, float* __restrict__ add_out)
{
    int tid = threadIdx.x;
    int b = blockIdx.x >> 6, r = blockIdx.x & 63;
    const float* x = ot + (size_t)(b * RR + r) * DD;
    __shared__ float xs[DD];
    __shared__ float hsm[HH];
    __shared__ float rs[4], rq[4];
    float v0 = x[tid], v1 = x[tid + 256];
    float s = v0 + v1, q = v0 * v0 + v1 * v1;
    #pragma unroll
    for (int off = 32; off > 0; off >>= 1) { s += __shfl_xor(s, off); q += __shfl_xor(q, off); }
    if ((tid & 63) == 0) { rs[tid >> 6] = s; rq[tid >> 6] = q; }
    __syncthreads();
    s = rs[0] + rs[1] + rs[2] + rs[3];
    q = rq[0] + rq[1] + rq[2] + rq[3];
    float mean = s * (1.0f / DD);
    float var = q * (1.0f / DD) - mean * mean;
    float inv = rsqrtf(var + 1e-6f);
    xs[tid]       = (v0 - mean) * inv * scale[tid]       + bias[tid];
    xs[tid + 256] = (v1 - mean) * inv * scale[tid + 256] + bias[tid + 256];
    __syncthreads();
    if (tid < HH) {
        float acc = ba1[tid];
        for (int k = 0; k < DD; k++) acc = fmaf(xs[k], Wa1[k * HH + tid], acc);
        hsm[tid] = gelu_tanh(acc);
    }
    __syncthreads();
    int d0 = tid, d1 = tid + 256;
    float a0 = ba2[d0], a1 = ba2[d1];
    #pragma unroll 4
    for (int k = 0; k < HH; k++) {
        float hk = hsm[k];
        a0 = fmaf(hk, Wa2[k * DD + d0], a0);
        a1 = fmaf(hk, Wa2[k * DD + d1], a1);
    }
    add_out[(size_t)(b * RR + r) * DD + d0] = a0;
    add_out[(size_t)(b * RR + r) * DD + d1] = a1;
}

// ---------------- erase v2: parallel-LN + 2Mx2N MFMA GEMM1 + gelu + GEMM2 + in-wave softmax partials
__global__ __launch_bounds__(256) void erase_mfma_kernel(
    const float* __restrict__ mem, const float* __restrict__ scale,
    const float* __restrict__ bias, const short* __restrict__ We1T,
    const float* __restrict__ be1, const short* __restrict__ We2T,
    const float* __restrict__ be2, float* __restrict__ logits,
    float* __restrict__ pmax, float* __restrict__ psum)
{
    __shared__ short xn[32 * XN_LD];     // 33,280 B
    __shared__ short hsm[32 * H_LD];     //  8,704 B

    int tid = threadIdx.x;
    int b = blockIdx.x >> 8;
    int chunk = blockIdx.x & 255;
    int m0 = chunk * 32;

    // ---- LN: 8 threads per row; 16 independent float4 loads per thread ----
    {
        int row = tid >> 3, sub = tid & 7;
        const float4* srcv = (const float4*)(mem + (size_t)(b * MM + m0 + row) * DD);
        float4 v[16];
        float s = 0.f, q = 0.f;
        #pragma unroll
        for (int j = 0; j < 16; j++) v[j] = srcv[j * 8 + sub];
        #pragma unroll
        for (int j = 0; j < 16; j++) {
            s += v[j].x + v[j].y + v[j].z + v[j].w;
            q += v[j].x*v[j].x + v[j].y*v[j].y + v[j].z*v[j].z + v[j].w*v[j].w;
        }
        #pragma unroll
        for (int off = 1; off <= 4; off <<= 1) { s += __shfl_xor(s, off); q += __shfl_xor(q, off); }
        float mean = s * (1.0f / 512.0f);
        float var = q * (1.0f / 512.0f) - mean * mean;
        float inv = rsqrtf(var + 1e-6f);
        const float4* scv = (const float4*)scale;
        const float4* biv = (const float4*)bias;
        #pragma unroll
        for (int j = 0; j < 16; j++) {
            float4 sc = scv[j * 8 + sub], bi = biv[j * 8 + sub];
            bf16x4 o;
            o[0] = f2bf((v[j].x - mean) * inv * sc.x + bi.x);
            o[1] = f2bf((v[j].y - mean) * inv * sc.y + bi.y);
            o[2] = f2bf((v[j].z - mean) * inv * sc.z + bi.z);
            o[3] = f2bf((v[j].w - mean) * inv * sc.w + bi.w);
            *(bf16x4*)&xn[row * XN_LD + j * 32 + sub * 4] = o;
        }
    }
    __syncthreads();

    int w = tid >> 6, l = tid & 63;
    int lr = l & 15, g = l >> 4, kg = g * 8;

    // ---- GEMM1: [32 x 512] x [512 x 128]; wave w owns cols w*32..+31, rows 0..31 (2Mx2N)
    const short* bp0 = We1T + ((size_t)(w * 32 + lr) << 9) + kg;
    const short* bp1 = bp0 + (16 << 9);
    f32x4 acc00 = {0.f,0.f,0.f,0.f}, acc01 = acc00, acc10 = acc00, acc11 = acc00;
    #pragma unroll 4
    for (int ks = 0; ks < 16; ks++) {
        int k0 = ks * 32;
        bf16x8 a0 = *(const bf16x8*)&xn[lr * XN_LD + k0 + kg];
        bf16x8 a1 = *(const bf16x8*)&xn[(16 + lr) * XN_LD + k0 + kg];
        bf16x8 b0 = *(const bf16x8*)(bp0 + k0);
        bf16x8 b1 = *(const bf16x8*)(bp1 + k0);
        acc00 = __builtin_amdgcn_mfma_f32_16x16x32_bf16(a0, b0, acc00, 0, 0, 0);
        acc10 = __builtin_amdgcn_mfma_f32_16x16x32_bf16(a1, b0, acc10, 0, 0, 0);
        acc01 = __builtin_amdgcn_mfma_f32_16x16x32_bf16(a0, b1, acc01, 0, 0, 0);
        acc11 = __builtin_amdgcn_mfma_f32_16x16x32_bf16(a1, b1, acc11, 0, 0, 0);
    }
    // epilogue: +bias, gelu -> hsm (bf16)
    #pragma unroll
    for (int nf = 0; nf < 2; nf++) {
        int col = w * 32 + nf * 16 + lr;
        float bv = be1[col];
        f32x4 A0 = nf ? acc01 : acc00;
        f32x4 A1 = nf ? acc11 : acc10;
        #pragma unroll
        for (int rg = 0; rg < 4; rg++) {
            hsm[(g * 4 + rg) * H_LD + col]        = f2bf(gelu_tanh(A0[rg] + bv));
            hsm[(16 + g * 4 + rg) * H_LD + col]   = f2bf(gelu_tanh(A1[rg] + bv));
        }
    }
    __syncthreads();

    // ---- GEMM2: [32 x 128] x [128 x 64]; wave w owns cols w*16..+15, rows 0..31
    const short* bp2 = We2T + (w * 16 + lr) * 128 + kg;
    f32x4 c0 = {0.f,0.f,0.f,0.f}, c1 = c0;
    #pragma unroll
    for (int ks = 0; ks < 4; ks++) {
        int k0 = ks * 32;
        bf16x8 a0 = *(const bf16x8*)&hsm[lr * H_LD + k0 + kg];
        bf16x8 a1 = *(const bf16x8*)&hsm[(16 + lr) * H_LD + k0 + kg];
        bf16x8 bb = *(const bf16x8*)(bp2 + k0);
        c0 = __builtin_amdgcn_mfma_f32_16x16x32_bf16(a0, bb, c0, 0, 0, 0);
        c1 = __builtin_amdgcn_mfma_f32_16x16x32_bf16(a1, bb, c1, 0, 0, 0);
    }
    // ---- +bias, store logits, in-wave per-column (max, sumexp) over 32 rows ----
    {
        int col = w * 16 + lr;
        float bv = be2[col];
        float vv[8];
        #pragma unroll
        for (int rg = 0; rg < 4; rg++) {
            vv[rg]     = c0[rg] + bv;
            vv[4 + rg] = c1[rg] + bv;
            logits[(size_t)(b * MM + m0 + g * 4 + rg) * 64 + col]      = vv[rg];
            logits[(size_t)(b * MM + m0 + 16 + g * 4 + rg) * 64 + col] = vv[4 + rg];
        }
        float mx = vv[0];
        #pragma unroll
        for (int j = 1; j < 8; j++) mx = fmaxf(mx, vv[j]);
        float sm = 0.f;
        #pragma unroll
        for (int j = 0; j < 8; j++) sm += __expf(vv[j] - mx);
        #pragma unroll
        for (int off = 16; off <= 32; off <<= 1) {
            float om = __shfl_xor(mx, off);
            float os = __shfl_xor(sm, off);
            float nm = fmaxf(mx, om);
            sm = sm * __expf(mx - nm) + os * __expf(om - nm);
            mx = nm;
        }
        if (l < 16) {
            pmax[((size_t)b * 256 + chunk) * 64 + col] = mx;
            psum[((size_t)b * 256 + chunk) * 64 + col] = sm;
        }
    }
}

// ---------------- combine 256 chunk partials -> rmax, rinv ------------------
__global__ __launch_bounds__(256) void softmax_finalize_kernel(
    const float* __restrict__ pmax, const float* __restrict__ psum,
    float* __restrict__ rmax, float* __restrict__ rinv)
{
    int b = blockIdx.x;
    int g = threadIdx.x >> 6, r = threadIdx.x & 63;
    float mx = -1e30f, sm = 0.0f;
    for (int ch = g; ch < 256; ch += 4) {
        float m2 = pmax[((size_t)b * 256 + ch) * 64 + r];
        float s2 = psum[((size_t)b * 256 + ch) * 64 + r];
        float nm = fmaxf(mx, m2);
        sm = sm * __expf(mx - nm) + s2 * __expf(m2 - nm);
        mx = nm;
    }
    __shared__ float sx_[4][64], sm_[4][64];
    sx_[g][r] = mx; sm_[g][r] = sm;
    __syncthreads();
    if (threadIdx.x < 64) {
        float M_ = sx_[0][threadIdx.x], S_ = sm_[0][threadIdx.x];
        #pragma unroll
        for (int gg = 1; gg < 4; gg++) {
            float m2 = sx_[gg][threadIdx.x], s2 = sm_[gg][threadIdx.x];
            float nm = fmaxf(M_, m2);
            S_ = S_ * __expf(M_ - nm) + s2 * __expf(m2 - nm);
            M_ = nm;
        }
        rmax[b * 64 + threadIdx.x] = M_;
        rinv[b * 64 + threadIdx.x] = 1.0f / S_;
    }
}

// ---------------- scale+transpose add -> addT[b][d][r] bf16 (rinv folded in) ----------
__global__ __launch_bounds__(256) void scale_transpose_kernel(
    const float* __restrict__ add, const float* __restrict__ rinv,
    short* __restrict__ addT)
{
    int b = blockIdx.x;
    int t = threadIdx.x;
    const float* rv = rinv + b * 64;
    for (int i = 0; i < 128; i++) {
        int idx = t + i * 256;           // 0 .. 32767
        int d = idx >> 6, r = idx & 63;
        addT[(size_t)b * 32768 + idx] =
            f2bf(add[((size_t)b * 64 + r) * 512 + d] * rv[r]);
    }
}

// ---------------- apply (R3-validated version): ea = exp(logit-rmax) @ addT (MFMA) ----
// Block = 64 m-rows x 512 d. 4 waves, wave w owns d in [w*128, w*128+128). No LDS.
__global__ __launch_bounds__(256, 4) void apply_mfma_kernel(
    const float* __restrict__ mem, const float* __restrict__ logits,
    const short* __restrict__ addT, const float* __restrict__ rmax,
    float* __restrict__ out)
{
    int tid = threadIdx.x;
    int w = tid >> 6, l = tid & 63;
    int b = blockIdx.x >> 7;
    int mt = blockIdx.x & 127;
    int m0 = mt * 64;
    int lr = l & 15, kg = (l >> 4) * 8;
    int nbase = w * 128;
    const short* aT = addT + (size_t)b * 512 * 64;

    // per-lane rmax for its 16 r-slots (k0=0 and k0=32)
    float rm0[8], rm1[8];
    #pragma unroll
    for (int j = 0; j < 8; j++) {
        rm0[j] = rmax[b * 64 + kg + j];
        rm1[j] = rmax[b * 64 + 32 + kg + j];
    }

    for (int ms = 0; ms < 4; ms++) {
        int mrow = m0 + ms * 16 + lr;
        const float* lp = logits + (size_t)(b * MM + mrow) * 64 + kg;
        float w0[8], w1[8];
        #pragma unroll
        for (int j = 0; j < 8; j++) {
            w0[j] = __expf(lp[j]      - rm0[j]);
            w1[j] = __expf(lp[32 + j] - rm1[j]);
        }
        bf16x8 a0, a1;
        #pragma unroll
        for (int j = 0; j < 8; j++) { a0[j] = f2bf(w0[j]); a1[j] = f2bf(w1[j]); }

        f32x4 acc[8];
        #pragma unroll
        for (int nf = 0; nf < 8; nf++) {
            int d = nbase + nf * 16 + lr;
            bf16x8 b0 = *(const bf16x8*)&aT[d * 64 + kg];
            bf16x8 b1 = *(const bf16x8*)&aT[d * 64 + 32 + kg];
            f32x4 c = (f32x4){0.f, 0.f, 0.f, 0.f};
            c = __builtin_amdgcn_mfma_f32_16x16x32_bf16(a0, b0, c, 0, 0, 0);
            c = __builtin_amdgcn_mfma_f32_16x16x32_bf16(a1, b1, c, 0, 0, 0);
            acc[nf] = c;
        }
        // epilogue: out = mem + ea*(1-mem)
        #pragma unroll
        for (int nf = 0; nf < 8; nf++) {
            int d = nbase + nf * 16 + lr;
            #pragma unroll
            for (int rg = 0; rg < 4; rg++) {
                int m = m0 + ms * 16 + (l >> 4) * 4 + rg;
                size_t off = (size_t)(b * MM + m) * DD + d;
                float mv = mem[off];
                out[off] = fmaf(acc[nf][rg], 1.0f - mv, mv);
            }
        }
    }
}

extern "C" void kernel_launch(void* const* d_in, const int* in_sizes, int n_in,
                              void* d_out, int out_size, void* d_ws, size_t ws_size,
                              hipStream_t stream) {
    const float* memory = (const float*)d_in[0];
    const float* ot     = (const float*)d_in[1];
    const float* ln_e_s = (const float*)d_in[2];
    const float* ln_e_b = (const float*)d_in[3];
    const float* We1    = (const float*)d_in[4];
    const float* be1    = (const float*)d_in[5];
    const float* We2    = (const float*)d_in[6];
    const float* be2    = (const float*)d_in[7];
    const float* ln_a_s = (const float*)d_in[8];
    const float* ln_a_b = (const float*)d_in[9];
    const float* Wa1    = (const float*)d_in[10];
    const float* ba1    = (const float*)d_in[11];
    const float* Wa2    = (const float*)d_in[12];
    const float* ba2    = (const float*)d_in[13];
    float* out = (float*)d_out;

    float* ws      = (float*)d_ws;
    float* add_ws  = ws;                         // 262,144 floats
    float* logits  = ws + 262144;                // 4,194,304 floats
    float* pmaxw   = ws + 262144 + 4194304;      // 131,072 floats
    float* psumw   = pmaxw + 131072;             // 131,072
    float* rmaxw   = psumw + 131072;             // 512
    float* rinvw   = rmaxw + 512;                // 512
    short* We1T    = (short*)(rinvw + 512);      // 65,536 bf16
    short* We2T    = We1T + 128 * 512;           // 8,192 bf16
    short* addT    = We2T + 64 * 128;            // 262,144 bf16

    hipLaunchKernelGGL(prep_weights_kernel, dim3(288), dim3(256), 0, stream,
                       We1, We2, We1T, We2T);
    hipLaunchKernelGGL(add_path_kernel, dim3(BB * RR), dim3(256), 0, stream,
                       ot, ln_a_s, ln_a_b, Wa1, ba1, Wa2, ba2, add_ws);
    hipLaunchKernelGGL(erase_mfma_kernel, dim3(BB * 256), dim3(256), 0, stream,
                       memory, ln_e_s, ln_e_b, We1T, be1, We2T, be2, logits, pmaxw, psumw);
    hipLaunchKernelGGL(softmax_finalize_kernel, dim3(BB), dim3(256), 0, stream,
                       pmaxw, psumw, rmaxw, rinvw);
    hipLaunchKernelGGL(scale_transpose_kernel, dim3(BB), dim3(256), 0, stream,
                       add_ws, rinvw, addT);
    hipLaunchKernelGGL(apply_mfma_kernel, dim3(BB * 128), dim3(256), 0, stream,
                       memory, logits, addT, rmaxw, out);
}